// Round 8
// baseline (197.960 us; speedup 1.0000x reference)
//
#include <hip/hip_runtime.h>

typedef unsigned short u16;
typedef unsigned int u32;
typedef __attribute__((ext_vector_type(4))) float f32x4;
typedef __attribute__((ext_vector_type(8))) short s16x8;
typedef __attribute__((ext_vector_type(4))) short s16x4;

static constexpr int N_ = 4096;
static constexpr int D_ = 1024;

#define WAITV(N) asm volatile("s_waitcnt vmcnt(" #N ")" ::: "memory")
#define MEMCLOB() asm volatile("" ::: "memory")

__device__ __forceinline__ u16 f2bf(float f) {
  unsigned u = __float_as_uint(f);
  u += 0x7FFFu + ((u >> 16) & 1u);  // RNE
  return (u16)(u >> 16);
}
__device__ __forceinline__ float bf2f(u16 v) {
  return __uint_as_float((u32)v << 16);
}
__device__ __forceinline__ f32x4 zero4() {
  f32x4 z; z[0] = 0.f; z[1] = 0.f; z[2] = 0.f; z[3] = 0.f; return z;
}
__device__ __forceinline__ void gload16(const void* g, void* lds) {
  __builtin_amdgcn_global_load_lds(
      (const __attribute__((address_space(1))) u32*)g,
      (__attribute__((address_space(3))) u32*)lds, 16, 0, 0);
}

// ---------------- K0: prep (WpB, MB) + surprise norms ----------------
// blocks 0..15: WpB bf16; 16..143: M = Pow @ Wsum; 144..2191: row norms.
__global__ __launch_bounds__(256) void k_aux(
    const float* __restrict__ Wpm, const float* __restrict__ piw,
    const float* __restrict__ pw, const float* __restrict__ Sur,
    const float* __restrict__ sscale_p, const float* __restrict__ sbias_p,
    u16* __restrict__ WpB, u16* __restrict__ MB, float* __restrict__ sqs_ws) {
  __shared__ float Ws[64][65];
  int bid = blockIdx.x, tid = threadIdx.x;
  if (bid < 16) {
    size_t i0 = (size_t)bid * 4096;
    for (int idx = tid; idx < 4096; idx += 256)
      WpB[i0 + idx] = f2bf(piw[i0 + idx]);
    return;
  }
  if (bid < 144) {
    int idx2 = bid - 16;
    int b = idx2 >> 4, t = idx2 & 15;
    for (int idx = tid; idx < 4096; idx += 256) {
      float s = 0.f;
#pragma unroll
      for (int k = 0; k < 8; ++k)
        s += Wpm[((size_t)(b * 8 + k)) * 4096 + idx];
      Ws[idx >> 6][idx & 63] = s;
    }
    __syncthreads();
    u16* mb = MB + ((size_t)b << 16);
    for (int oidx = tid; oidx < 4096; oidx += 256) {
      int r = oidx >> 6, c = oidx & 63;
      int drow = t * 64 + r;
      const float* prow = pw + (size_t)drow * 64;
      float acc = 0.f;
#pragma unroll 8
      for (int q = 0; q < 64; ++q) acc += prow[q] * Ws[q][c];
      mb[(size_t)drow * 64 + c] = f2bf(acc);
    }
    return;
  }
  // ---- norms: 4 waves, 4 rows each ----
  int w = tid >> 6, lane = tid & 63;
  int fr = (bid - 144) * 16 + w * 4;
  const float4* r0 = (const float4*)(Sur + (size_t)fr * 1024) + lane;
  float s0 = 0.f, s1 = 0.f, s2 = 0.f, s3 = 0.f;
#pragma unroll
  for (int c = 0; c < 4; ++c) {
    float4 v0 = r0[c * 64];
    float4 v1 = r0[256 + c * 64];
    float4 v2 = r0[512 + c * 64];
    float4 v3 = r0[768 + c * 64];
    s0 += v0.x * v0.x + v0.y * v0.y + v0.z * v0.z + v0.w * v0.w;
    s1 += v1.x * v1.x + v1.y * v1.y + v1.z * v1.z + v1.w * v1.w;
    s2 += v2.x * v2.x + v2.y * v2.y + v2.z * v2.z + v2.w * v2.w;
    s3 += v3.x * v3.x + v3.y * v3.y + v3.z * v3.z + v3.w * v3.w;
  }
#pragma unroll
  for (int m = 1; m < 64; m <<= 1) {
    s0 += __shfl_xor(s0, m, 64);
    s1 += __shfl_xor(s1, m, 64);
    s2 += __shfl_xor(s2, m, 64);
    s3 += __shfl_xor(s3, m, 64);
  }
  float res = s0;
  if (lane == 1) res = s1;
  if (lane == 2) res = s2;
  if (lane == 3) res = s3;
  if (lane < 4) {
    float mag = sqrtf(res);
    float s = 1.f / (1.f + __expf(-(sscale_p[0] * mag + sbias_p[0])));
    sqs_ws[fr + lane] = sqrtf(s);
  }
}

// ---------------- K1: fused read/commit main pass ----------------
// 2048 blocks (8 b x 256 tiles of 16 rows), 256 threads (4 waves).
// wave w owns K-quarter (phase A), p-quarter (phase G), N-quarter (phase D).
// Phase A barrier-free: private 2KB LDS slot per wave, counted vmcnt.
__global__ __launch_bounds__(256, 6) void k_main(
    const float* __restrict__ H, const float* __restrict__ pib,
    const float* __restrict__ pob, const u16* __restrict__ WpB,
    const u16* __restrict__ MB, const float* __restrict__ sqs_ws,
    u16* __restrict__ GpartB, float* __restrict__ out) {
  // staging: 2 bufs x 4 waves x 2KB = [0,16384)
  // epilogue (staging dead): preF f32[3][16][66] @0 (12672),
  // preRP u16[16][72] @12672 (2304), wRPT u16[64][40] @14976 (5120) -> 20096.
  __shared__ __align__(16) char arena[20096];

  const int tid = threadIdx.x;
  const int lane = tid & 63;
  const int w = tid >> 6;
  const int llo = lane & 15;
  const int lhi = lane >> 4;
  const int b = blockIdx.x >> 8;
  const int row0 = (blockIdx.x & 255) * 16;  // 256 tiles x 16 rows = 4096 OK

  // small operands into regs early
  float bias_t[4];
#pragma unroll
  for (int t = 0; t < 4; ++t) bias_t[t] = pib[t * 16 + llo];
  float sqs_r[4];
#pragma unroll
  for (int r = 0; r < 4; ++r)
    sqs_r[r] = sqs_ws[b * 4096 + row0 + lhi * 4 + r];

  // ---- phase A staging geometry (per-wave private, K-quarter = 256) ----
  const int c16 = (lane & 7) ^ (lane >> 3);  // XOR swizzle on global side
  const float* hsrc0 =
      H + ((size_t)b * N_ + row0 + (lane >> 3)) * D_ + w * 256 + c16 * 4;
  const float* hsrc1 = hsrc0 + 8 * D_;
  char* wbase = arena + w * 2048;  // + (kc&1)*8192 per buffer
  const u16* wpb = WpB + w * 256 + lhi * 8;

  f32x4 accA[4];
#pragma unroll
  for (int t = 0; t < 4; ++t) accA[t] = zero4();
  s16x8 Bf[2][4];

#define STAGEH(kc)                                                     \
  gload16(hsrc0 + (kc) * 32, wbase + ((kc) & 1) * 8192);               \
  gload16(hsrc1 + (kc) * 32, wbase + ((kc) & 1) * 8192 + 1024)

#define LOADB(kc)                                                      \
  _Pragma("unroll") for (int t = 0; t < 4; ++t) Bf[(kc) & 1][t] =      \
      *(const s16x8*)(wpb + (size_t)(t * 16 + llo) * 1024 + (kc) * 32)

  // issue order pinned: S0 B0 S1 B1  (S=2 vmem ops, B=4)
  STAGEH(0); MEMCLOB();
  LOADB(0);  MEMCLOB();
  STAGEH(1); MEMCLOB();
  LOADB(1);  MEMCLOB();

  // read offsets within the wave's 2KB slot (undo source swizzle)
  const int jblk = (llo >> 3) * 1024;
  const int r7 = llo & 7;
  const int slot_lo = r7 * 8 + ((lhi * 2) ^ r7);
  const int slot_hi = r7 * 8 + ((lhi * 2 + 1) ^ r7);

#pragma unroll
  for (int kc = 0; kc < 8; ++kc) {
    if (kc <= 6) { WAITV(6); } else { WAITV(0); }
    {
      const char* base = arena + (kc & 1) * 8192 + w * 2048 + jblk;
      f32x4 alo = *(const f32x4*)(base + slot_lo * 16);
      f32x4 ahi = *(const f32x4*)(base + slot_hi * 16);
      s16x8 af;
      af[0] = (short)f2bf(alo[0]); af[1] = (short)f2bf(alo[1]);
      af[2] = (short)f2bf(alo[2]); af[3] = (short)f2bf(alo[3]);
      af[4] = (short)f2bf(ahi[0]); af[5] = (short)f2bf(ahi[1]);
      af[6] = (short)f2bf(ahi[2]); af[7] = (short)f2bf(ahi[3]);
#pragma unroll
      for (int t = 0; t < 4; ++t)
        accA[t] = __builtin_amdgcn_mfma_f32_16x16x32_bf16(af, Bf[kc & 1][t],
                                                          accA[t], 0, 0, 0);
    }
    MEMCLOB();
    if (kc + 2 < 8) { LOADB(kc + 2); MEMCLOB(); STAGEH(kc + 2); MEMCLOB(); }
  }
#undef STAGEH
#undef LOADB

  // ---- epilogue: combine K-quarters across waves ----
  __syncthreads();  // all staging reads done; arena reusable
  float* preF = (float*)arena;                 // [3][16][66] : j*1056+row*66+col
  u16* preRP = (u16*)(arena + 12672);          // [16][72]
  u16* wRPT = (u16*)(arena + 14976);           // [64][40]  ([p][row], rows 16..31 zero)

  if (w > 0) {
#pragma unroll
    for (int t = 0; t < 4; ++t)
#pragma unroll
      for (int r = 0; r < 4; ++r)
        preF[(w - 1) * 1056 + (lhi * 4 + r) * 66 + t * 16 + llo] = accA[t][r];
  }
  __syncthreads();
  if (w == 0) {
#pragma unroll
    for (int t = 0; t < 4; ++t)
#pragma unroll
      for (int r = 0; r < 4; ++r) {
        int row = lhi * 4 + r;
        int col = t * 16 + llo;
        float v = accA[t][r] + preF[row * 66 + col] +
                  preF[1056 + row * 66 + col] + preF[2112 + row * 66 + col] +
                  bias_t[t];
        preRP[row * 72 + col] = f2bf(v);
        wRPT[col * 40 + row] = f2bf(v * sqs_r[r]);
      }
  }
  {  // zero wRPT pad rows 16..31 (64 p x 16 rows / 256 threads = short4 each)
    int p = tid >> 2, q = tid & 3;
    s16x4 z4; z4[0] = 0; z4[1] = 0; z4[2] = 0; z4[3] = 0;
    *(s16x4*)&wRPT[p * 40 + 16 + q * 4] = z4;
  }
  __syncthreads();

  // ---- phase G: per-block partial G = weighted^T @ weighted (16 rows) ----
  {
    s16x8 ag = *(const s16x8*)&wRPT[(w * 16 + llo) * 40 + lhi * 8];
    f32x4 accG[4];
#pragma unroll
    for (int t1 = 0; t1 < 4; ++t1) {
      s16x8 bg = *(const s16x8*)&wRPT[(t1 * 16 + llo) * 40 + lhi * 8];
      accG[t1] =
          __builtin_amdgcn_mfma_f32_16x16x32_bf16(ag, bg, zero4(), 0, 0, 0);
    }
    u16* gout = GpartB + (size_t)blockIdx.x * 4096;
#pragma unroll
    for (int t1 = 0; t1 < 4; ++t1)
#pragma unroll
      for (int r = 0; r < 4; ++r)
        gout[(w * 16 + lhi * 4 + r) * 64 + t1 * 16 + llo] = f2bf(accG[t1][r]);
  }

  // ---- phase D: pm_read = pre @ M^T + bias (wave w: N-quarter) ----
  // operand-swapped mfma(Mfrag, prefrag): lane holds 4 consecutive n-cols
  // of one pre-row -> float4 stores.
  {
    s16x8 ad0 = *(const s16x8*)&preRP[llo * 72 + lhi * 8];
    s16x8 ad1 = *(const s16x8*)&preRP[llo * 72 + 32 + lhi * 8];
    const u16* mcol =
        MB + ((size_t)b << 16) + (size_t)(w * 256) * 64 + lhi * 8;
    float* orow = out + ((size_t)b * N_ + row0 + llo) * D_ + w * 256;
    const float* pobw = pob + w * 256;
#pragma unroll
    for (int c = 0; c < 4; ++c) {
      s16x8 f0[4], f1[4];
#pragma unroll
      for (int i = 0; i < 4; ++i) {
        const u16* p = mcol + (size_t)(c * 64 + i * 16 + llo) * 64;
        f0[i] = *(const s16x8*)p;
        f1[i] = *(const s16x8*)(p + 32);
      }
#pragma unroll
      for (int i = 0; i < 4; ++i) {
        f32x4 acc = zero4();
        acc = __builtin_amdgcn_mfma_f32_16x16x32_bf16(f0[i], ad0, acc, 0, 0, 0);
        acc = __builtin_amdgcn_mfma_f32_16x16x32_bf16(f1[i], ad1, acc, 0, 0, 0);
        int n0 = c * 64 + i * 16 + lhi * 4;
        float4 bias4 = *(const float4*)&pobw[n0];
        float4 o;
        o.x = acc[0] + bias4.x;
        o.y = acc[1] + bias4.y;
        o.z = acc[2] + bias4.z;
        o.w = acc[3] + bias4.w;
        *(float4*)(orow + n0) = o;
      }
    }
  }
}

// ---------------- K2: reduce GpartB (bf16, 256 slabs/batch) -> Gsum (f32) ----------------
__global__ __launch_bounds__(256) void k_gred(
    const u16* __restrict__ GpartB, float* __restrict__ Gsum) {
  __shared__ float red[4][64];
  int b = blockIdx.x >> 6, g = blockIdx.x & 63;
  int lane = threadIdx.x & 63, q = threadIdx.x >> 6;
  const u16* src = GpartB + ((size_t)(b * 256 + q * 64)) * 4096 + g * 64 + lane;
  float s = 0.f;
#pragma unroll 8
  for (int i = 0; i < 64; ++i) s += bf2f(src[(size_t)i * 4096]);
  red[q][lane] = s;
  __syncthreads();
  if (q == 0)
    Gsum[(size_t)b * 4096 + g * 64 + lane] =
        red[0][lane] + red[1][lane] + red[2][lane] + red[3][lane];
}

// ---------------- K3: W_new = W_pm @ (decay*I + beta*G/N), frob clip ----------------
__global__ __launch_bounds__(256) void k_wnew(
    const float* __restrict__ Wpm, const float* __restrict__ Gsum,
    const float* __restrict__ rbeta, const float* __restrict__ rdecay,
    float* __restrict__ outW) {
  __shared__ float Wk[64][66];
  __shared__ float Gl[64][66];
  __shared__ float red[4];
  int bk = blockIdx.x;
  int b = bk >> 3, k = bk & 7;
  int tid = threadIdx.x;
  const float* wsrc = Wpm + (size_t)bk * 4096;
  const float* gsrc = Gsum + (size_t)b * 4096;
  for (int idx = tid; idx < 4096; idx += 256) {
    Wk[idx >> 6][idx & 63] = wsrc[idx];
    Gl[idx >> 6][idx & 63] = gsrc[idx];
  }
  __syncthreads();
  float beta = log1pf(__expf(rbeta[k]));
  float decay = 1.f / (1.f + __expf(-rdecay[k]));
  float bn = beta * (1.f / 4096.f);  // G partials are unnormalized
  int q = tid & 63;
  int rbase = tid >> 6;
  float vals[16];
  float ss = 0.f;
#pragma unroll
  for (int i = 0; i < 16; ++i) {
    int row = i * 4 + rbase;
    float acc = 0.f;
#pragma unroll 8
    for (int j = 0; j < 64; ++j) acc += Wk[row][j] * Gl[j][q];
    float v = decay * Wk[row][q] + bn * acc;
    vals[i] = v;
    ss += v * v;
  }
#pragma unroll
  for (int m = 1; m < 64; m <<= 1) ss += __shfl_xor(ss, m, 64);
  if ((tid & 63) == 0) red[tid >> 6] = ss;
  __syncthreads();
  float frob = sqrtf(red[0] + red[1] + red[2] + red[3]);
  float scale = fminf(16.f / fmaxf(frob, 1e-8f), 1.f);
  float* dst = outW + (size_t)bk * 4096;
#pragma unroll
  for (int i = 0; i < 16; ++i) dst[i * 256 + tid] = vals[i] * scale;
}

extern "C" void kernel_launch(void* const* d_in, const int* in_sizes, int n_in,
                              void* d_out, int out_size, void* d_ws, size_t ws_size,
                              hipStream_t stream) {
  const float* H      = (const float*)d_in[0];
  const float* Sur    = (const float*)d_in[1];
  const float* Wpm    = (const float*)d_in[2];
  const float* piw    = (const float*)d_in[3];
  const float* pib    = (const float*)d_in[4];
  const float* pw     = (const float*)d_in[5];
  const float* pob    = (const float*)d_in[6];
  const float* rbeta  = (const float*)d_in[7];
  const float* rdecay = (const float*)d_in[8];
  const float* sscale = (const float*)d_in[9];
  const float* sbias  = (const float*)d_in[10];
  float* out = (float*)d_out;

  char* ws = (char*)d_ws;
  u16* WpB      = (u16*)(ws);               // [64][1024] bf16      = 131072 B
  u16* MB       = (u16*)(ws + 131072);      // [8][1024][64] bf16   = 1 MB
  float* sqs_ws = (float*)(ws + 1179648);   // [8][4096] f32        = 131072 B
  float* Gsum   = (float*)(ws + 1310720);   // [8][64][64] f32      = 131072 B
  u16* GpartB   = (u16*)(ws + 1441792);     // [2048][64][64] bf16  = 16 MB

  k_aux<<<2192, 256, 0, stream>>>(Wpm, piw, pw, Sur, sscale, sbias,
                                  WpB, MB, sqs_ws);
  k_main<<<2048, 256, 0, stream>>>(H, pib, pob, WpB, MB, sqs_ws, GpartB, out);
  k_gred<<<512, 256, 0, stream>>>(GpartB, Gsum);
  k_wnew<<<64, 256, 0, stream>>>(Wpm, Gsum, rbeta, rdecay,
                                 out + (size_t)8 * 4096 * 1024);
}

// Round 9
// 140.388 us; speedup vs baseline: 1.4101x; 1.4101x over previous
//
#include <hip/hip_runtime.h>

typedef unsigned short u16;
typedef unsigned int u32;
typedef __attribute__((ext_vector_type(4))) float f32x4;
typedef __attribute__((ext_vector_type(8))) short s16x8;

static constexpr int N_ = 4096;
static constexpr int D_ = 1024;

#define WAITV(N) asm volatile("s_waitcnt vmcnt(" #N ")" ::: "memory")
#define MEMCLOB() asm volatile("" ::: "memory")

__device__ __forceinline__ u16 f2bf(float f) {
  unsigned u = __float_as_uint(f);
  u += 0x7FFFu + ((u >> 16) & 1u);  // RNE
  return (u16)(u >> 16);
}
__device__ __forceinline__ f32x4 zero4() {
  f32x4 z; z[0] = 0.f; z[1] = 0.f; z[2] = 0.f; z[3] = 0.f; return z;
}
__device__ __forceinline__ void gload16(const void* g, void* lds) {
  __builtin_amdgcn_global_load_lds(
      (const __attribute__((address_space(1))) u32*)g,
      (__attribute__((address_space(3))) u32*)lds, 16, 0, 0);
}

// ---------------- K0: prep WpB bf16 + M = Pow @ Wsum ----------------
__global__ __launch_bounds__(256) void k_aux(
    const float* __restrict__ Wpm, const float* __restrict__ piw,
    const float* __restrict__ pw, u16* __restrict__ WpB,
    u16* __restrict__ MB) {
  __shared__ float Ws[64][65];
  int bid = blockIdx.x, tid = threadIdx.x;
  if (bid < 16) {
    size_t i0 = (size_t)bid * 4096;
    for (int idx = tid; idx < 4096; idx += 256)
      WpB[i0 + idx] = f2bf(piw[i0 + idx]);
    return;
  }
  int idx2 = bid - 16;
  int b = idx2 >> 4, t = idx2 & 15;
  for (int idx = tid; idx < 4096; idx += 256) {
    float s = 0.f;
#pragma unroll
    for (int k = 0; k < 8; ++k)
      s += Wpm[((size_t)(b * 8 + k)) * 4096 + idx];
    Ws[idx >> 6][idx & 63] = s;
  }
  __syncthreads();
  u16* mb = MB + ((size_t)b << 16);
  for (int oidx = tid; oidx < 4096; oidx += 256) {
    int r = oidx >> 6, c = oidx & 63;
    int drow = t * 64 + r;
    const float* prow = pw + (size_t)drow * 64;
    float acc = 0.f;
#pragma unroll 8
    for (int q = 0; q < 64; ++q) acc += prow[q] * Ws[q][c];
    mb[(size_t)drow * 64 + c] = f2bf(acc);
  }
}

// ---------------- K1: fused norm + read/commit main pass ----------------
// 512 blocks (8 b x 64 tiles of 64 rows), 512 threads (8 waves).
// wave w: wm = w&3 -> 16-row tile, wk = w>>2 -> K-half / N-half.
// Round-4 proven barrier-coupled pipeline; Sur row-norm loads interleaved
// (2 float4/half-chunk, 2-deep rolling regs), groups 6->8, WAITV 6->8.
__global__ __launch_bounds__(512, 4) void k_main(
    const float* __restrict__ H, const float* __restrict__ Sur,
    const float* __restrict__ pib, const float* __restrict__ pob,
    const float* __restrict__ sscale_p, const float* __restrict__ sbias_p,
    const u16* __restrict__ WpB, const u16* __restrict__ MB,
    float* __restrict__ Gpart, float* __restrict__ out) {
  __shared__ __align__(16) char arena[32768];  // staging / preF reuse
  __shared__ __align__(16) u16 preRP[64][72];
  __shared__ __align__(16) u16 wRPT[64][72];
  __shared__ float pobL[1024];
  __shared__ float sqsL[64];

  const int tid = threadIdx.x;
  const int lane = tid & 63;
  const int w = tid >> 6;
  const int wm = w & 3;
  const int wk = w >> 2;
  const int llo = lane & 15;
  const int lhi = lane >> 4;
  const int b = blockIdx.x >> 6;
  const int row0 = (blockIdx.x & 63) * 64;

  // small operands into regs early (oldest vmem, drained by first WAITV)
  float bias_t[4];
#pragma unroll
  for (int t = 0; t < 4; ++t) bias_t[t] = pib[t * 16 + llo];
  const float sscale = sscale_p[0], sbias = sbias_p[0];

  // ---- staging geometry ----
  const int srow = 8 * w + (lane >> 3);
  const int sc16 = (lane & 7) ^ (srow & 7);
  const float* hsrc = H + ((size_t)b * N_ + row0 + srow) * D_ + sc16 * 4;
  const u16* wpb = WpB + (size_t)wk * 512 + lhi * 8;
  // Sur: thread covers row (tid>>3), 8 threads/row, 128 floats each
  const float* surp =
      Sur + ((size_t)b * N_ + row0 + (tid >> 3)) * D_ + (tid & 7) * 4;

  f32x4 accA[4];
#pragma unroll
  for (int t = 0; t < 4; ++t) accA[t] = zero4();
  s16x8 B0[4], B1[4];
  float4 surR0[2], surR1[2];
  float ssq = 0.f;

  auto LOADB = [&](int kc, s16x8* Bs) {
#pragma unroll
    for (int t = 0; t < 4; ++t)
      Bs[t] = *(const s16x8*)(wpb + (size_t)(t * 16 + llo) * 1024 + kc * 32);
  };
  auto STAGEH = [&](int kc, int buf) {
    gload16(hsrc + kc * 32, arena + buf * 16384 + w * 1024);
    gload16(hsrc + 512 + kc * 32, arena + buf * 16384 + 8192 + w * 1024);
  };
  const int arow = wm * 16 + llo;
  const int r7a = arow & 7;
  auto COMPA = [&](int buf, const s16x8* Bs) {
    const char* abase = arena + buf * 16384 + wk * 8192 + arow * 128;
    f32x4 alo = *(const f32x4*)(abase + (((lhi * 2) ^ r7a) * 16));
    f32x4 ahi = *(const f32x4*)(abase + (((lhi * 2 + 1) ^ r7a) * 16));
    s16x8 af;
    af[0] = (short)f2bf(alo[0]); af[1] = (short)f2bf(alo[1]);
    af[2] = (short)f2bf(alo[2]); af[3] = (short)f2bf(alo[3]);
    af[4] = (short)f2bf(ahi[0]); af[5] = (short)f2bf(ahi[1]);
    af[6] = (short)f2bf(ahi[2]); af[7] = (short)f2bf(ahi[3]);
#pragma unroll
    for (int t = 0; t < 4; ++t)
      accA[t] = __builtin_amdgcn_mfma_f32_16x16x32_bf16(af, Bs[t], accA[t], 0, 0, 0);
  };

  // prologue order pinned: G0 S0 G1 S1  (G = 4 B-loads + 2 stages, S = 2 Sur)
  LOADB(0, B0); STAGEH(0, 0);
  MEMCLOB();
  surR0[0] = *(const float4*)(surp);
  surR0[1] = *(const float4*)(surp + 32);
  MEMCLOB();
  LOADB(1, B1); STAGEH(1, 1);
  MEMCLOB();
  surR1[0] = *(const float4*)(surp + 64);
  surR1[1] = *(const float4*)(surp + 96);
  MEMCLOB();

  for (int kc = 0; kc < 16; kc += 2) {
    WAITV(8);
    __builtin_amdgcn_s_barrier();
    COMPA(0, B0);
    ssq += surR0[0].x * surR0[0].x + surR0[0].y * surR0[0].y +
           surR0[0].z * surR0[0].z + surR0[0].w * surR0[0].w +
           surR0[1].x * surR0[1].x + surR0[1].y * surR0[1].y +
           surR0[1].z * surR0[1].z + surR0[1].w * surR0[1].w;
    MEMCLOB();
    __builtin_amdgcn_s_barrier();
    if (kc + 2 < 16) {
      LOADB(kc + 2, B0); STAGEH(kc + 2, 0);
      MEMCLOB();
      surR0[0] = *(const float4*)(surp + (kc + 2) * 64);
      surR0[1] = *(const float4*)(surp + (kc + 2) * 64 + 32);
    }
    MEMCLOB();
    if (kc + 1 == 15) { WAITV(0); } else { WAITV(8); }
    __builtin_amdgcn_s_barrier();
    COMPA(1, B1);
    ssq += surR1[0].x * surR1[0].x + surR1[0].y * surR1[0].y +
           surR1[0].z * surR1[0].z + surR1[0].w * surR1[0].w +
           surR1[1].x * surR1[1].x + surR1[1].y * surR1[1].y +
           surR1[1].z * surR1[1].z + surR1[1].w * surR1[1].w;
    MEMCLOB();
    __builtin_amdgcn_s_barrier();
    if (kc + 3 < 16) {
      LOADB(kc + 3, B1); STAGEH(kc + 3, 1);
      MEMCLOB();
      surR1[0] = *(const float4*)(surp + (kc + 3) * 64);
      surR1[1] = *(const float4*)(surp + (kc + 3) * 64 + 32);
    }
    MEMCLOB();
  }

  // ---- row-norm finish: reduce over the 8 threads of each row ----
  {
    float a = ssq;
    a += __shfl_xor(a, 1, 64);
    a += __shfl_xor(a, 2, 64);
    a += __shfl_xor(a, 4, 64);
    if ((lane & 7) == 0) {
      float mag = sqrtf(a);
      float s = 1.f / (1.f + __expf(-(sscale * mag + sbias)));
      sqsL[w * 8 + (lane >> 3)] = sqrtf(s);
    }
  }

  // ---- epilogue: combine K-halves, write pre/weighted ----
  __syncthreads();
  float (*preF)[65] = (float(*)[65])arena;
  if (wk == 1) {
#pragma unroll
    for (int t = 0; t < 4; ++t)
#pragma unroll
      for (int r = 0; r < 4; ++r)
        preF[wm * 16 + lhi * 4 + r][t * 16 + llo] = accA[t][r];
  }
  __syncthreads();
  if (wk == 0) {
    float sqs_r[4];
#pragma unroll
    for (int r = 0; r < 4; ++r) sqs_r[r] = sqsL[wm * 16 + lhi * 4 + r];
#pragma unroll
    for (int t = 0; t < 4; ++t)
#pragma unroll
      for (int r = 0; r < 4; ++r) {
        int row = wm * 16 + lhi * 4 + r;
        float v = accA[t][r] + preF[row][t * 16 + llo] + bias_t[t];
        preRP[row][t * 16 + llo] = f2bf(v);
        wRPT[t * 16 + llo][row] = f2bf(v * sqs_r[r]);
      }
  }
  __syncthreads();

  // ---- phase G: per-block partial G ----
  {
    f32x4 accG[4];
#pragma unroll
    for (int t = 0; t < 4; ++t) accG[t] = zero4();
    s16x8 ag = *(const s16x8*)&wRPT[wm * 16 + llo][wk * 32 + lhi * 8];
#pragma unroll
    for (int t = 0; t < 4; ++t) {
      s16x8 bg = *(const s16x8*)&wRPT[t * 16 + llo][wk * 32 + lhi * 8];
      accG[t] = __builtin_amdgcn_mfma_f32_16x16x32_bf16(ag, bg, accG[t], 0, 0, 0);
    }
    float* gout = Gpart + ((size_t)blockIdx.x * 2 + wk) * 4096;
#pragma unroll
    for (int t = 0; t < 4; ++t)
#pragma unroll
      for (int r = 0; r < 4; ++r)
        gout[(wm * 16 + lhi * 4 + r) * 64 + t * 16 + llo] = accG[t][r];
  }
  pobL[tid] = pob[tid];
  pobL[tid + 512] = pob[tid + 512];
  __syncthreads();  // drains; arena free for MB staging

  // ---- phase D: pm_read = pre @ M^T + bias (LDS-staged, WAITV-counted) ----
  const u16* mbb = MB + ((size_t)b << 16);
  const u16* msrc0 = mbb + (size_t)srow * 64 + sc16 * 8;
  auto STAGED = [&](int c, int buf) {
    gload16(msrc0 + (size_t)c * 64 * 64, arena + buf * 16384 + w * 1024);
    gload16(msrc0 + (size_t)(512 + c * 64) * 64, arena + buf * 16384 + 8192 + w * 1024);
  };
  s16x8 ad0 = *(const s16x8*)&preRP[wm * 16 + llo][lhi * 8];
  s16x8 ad1 = *(const s16x8*)&preRP[wm * 16 + llo][32 + lhi * 8];
  float* orow = out + ((size_t)b * N_ + row0 + wm * 16) * D_;

  STAGED(0, 0);
  MEMCLOB();
  STAGED(1, 1);
  MEMCLOB();
  for (int c = 0; c < 8; ++c) {
    if (c == 0) { WAITV(2); }
    else if (c == 7) { WAITV(16); }
    else { WAITV(18); }
    __builtin_amdgcn_s_barrier();
    {
      const char* dbase = arena + (c & 1) * 16384 + wk * 8192;
#pragma unroll
      for (int i = 0; i < 4; ++i) {
        int row = i * 16 + llo;
        int r7 = row & 7;
        const char* base = dbase + row * 128;
        s16x8 b0 = *(const s16x8*)(base + ((lhi ^ r7) * 16));
        s16x8 b1 = *(const s16x8*)(base + (((4 + lhi) ^ r7) * 16));
        f32x4 acc = zero4();
        acc = __builtin_amdgcn_mfma_f32_16x16x32_bf16(ad0, b0, acc, 0, 0, 0);
        acc = __builtin_amdgcn_mfma_f32_16x16x32_bf16(ad1, b1, acc, 0, 0, 0);
        int n0 = wk * 512 + c * 64 + i * 16;
        float bias = pobL[n0 + llo];
#pragma unroll
        for (int r = 0; r < 4; ++r)
          orow[(size_t)(lhi * 4 + r) * D_ + n0 + llo] = acc[r] + bias;
      }
    }
    MEMCLOB();
    __builtin_amdgcn_s_barrier();
    if (c + 2 < 8) STAGED(c + 2, c & 1);
    MEMCLOB();
  }
}

// ---------------- K2: reduce Gpart -> Gsum ----------------
__global__ __launch_bounds__(256) void k_gred(
    const float* __restrict__ Gpart, float* __restrict__ Gsum) {
  __shared__ float red[4][64];
  int b = blockIdx.x >> 6, g = blockIdx.x & 63;
  int lane = threadIdx.x & 63, q = threadIdx.x >> 6;
  const float* src = Gpart + ((size_t)b * 128 + q * 32) * 4096 + g * 64 + lane;
  float s = 0.f;
#pragma unroll 8
  for (int i = 0; i < 32; ++i) s += src[(size_t)i * 4096];
  red[q][lane] = s;
  __syncthreads();
  if (q == 0)
    Gsum[(size_t)b * 4096 + g * 64 + lane] =
        red[0][lane] + red[1][lane] + red[2][lane] + red[3][lane];
}

// ---------------- K3: W_new = W_pm @ (decay*I + beta*G/N), frob clip ----------------
__global__ __launch_bounds__(256) void k_wnew(
    const float* __restrict__ Wpm, const float* __restrict__ Gsum,
    const float* __restrict__ rbeta, const float* __restrict__ rdecay,
    float* __restrict__ outW) {
  __shared__ float Wk[64][66];
  __shared__ float Gl[64][66];
  __shared__ float red[4];
  int bk = blockIdx.x;
  int b = bk >> 3, k = bk & 7;
  int tid = threadIdx.x;
  const float* wsrc = Wpm + (size_t)bk * 4096;
  const float* gsrc = Gsum + (size_t)b * 4096;
  for (int idx = tid; idx < 4096; idx += 256) {
    Wk[idx >> 6][idx & 63] = wsrc[idx];
    Gl[idx >> 6][idx & 63] = gsrc[idx];
  }
  __syncthreads();
  float beta = log1pf(__expf(rbeta[k]));
  float decay = 1.f / (1.f + __expf(-rdecay[k]));
  float bn = beta * (1.f / 4096.f);  // G partials are unnormalized
  int q = tid & 63;
  int rbase = tid >> 6;
  float vals[16];
  float ss = 0.f;
#pragma unroll
  for (int i = 0; i < 16; ++i) {
    int row = i * 4 + rbase;
    float acc = 0.f;
#pragma unroll 8
    for (int j = 0; j < 64; ++j) acc += Wk[row][j] * Gl[j][q];
    float v = decay * Wk[row][q] + bn * acc;
    vals[i] = v;
    ss += v * v;
  }
#pragma unroll
  for (int m = 1; m < 64; m <<= 1) ss += __shfl_xor(ss, m, 64);
  if ((tid & 63) == 0) red[tid >> 6] = ss;
  __syncthreads();
  float frob = sqrtf(red[0] + red[1] + red[2] + red[3]);
  float scale = fminf(16.f / fmaxf(frob, 1e-8f), 1.f);
  float* dst = outW + (size_t)bk * 4096;
#pragma unroll
  for (int i = 0; i < 16; ++i) dst[i * 256 + tid] = vals[i] * scale;
}

extern "C" void kernel_launch(void* const* d_in, const int* in_sizes, int n_in,
                              void* d_out, int out_size, void* d_ws, size_t ws_size,
                              hipStream_t stream) {
  const float* H      = (const float*)d_in[0];
  const float* Sur    = (const float*)d_in[1];
  const float* Wpm    = (const float*)d_in[2];
  const float* piw    = (const float*)d_in[3];
  const float* pib    = (const float*)d_in[4];
  const float* pw     = (const float*)d_in[5];
  const float* pob    = (const float*)d_in[6];
  const float* rbeta  = (const float*)d_in[7];
  const float* rdecay = (const float*)d_in[8];
  const float* sscale = (const float*)d_in[9];
  const float* sbias  = (const float*)d_in[10];
  float* out = (float*)d_out;

  char* ws = (char*)d_ws;
  u16* WpB     = (u16*)(ws);                  // [64][1024] bf16    = 131072 B
  u16* MB      = (u16*)(ws + 131072);         // [8][1024][64] bf16 = 1 MB
  float* Gsum  = (float*)(ws + 1179648);      // [8][64][64] f32    = 131072 B
  float* Gpart = (float*)(ws + 1310720);      // [1024][64][64] f32 = 16 MB

  k_aux<<<144, 256, 0, stream>>>(Wpm, piw, pw, WpB, MB);
  k_main<<<512, 512, 0, stream>>>(H, Sur, pib, pob, sscale, sbias,
                                  WpB, MB, Gpart, out);
  k_gred<<<512, 256, 0, stream>>>(Gpart, Gsum);
  k_wnew<<<64, 256, 0, stream>>>(Wpm, Gsum, rbeta, rdecay,
                                 out + (size_t)8 * 4096 * 1024);
}